// Round 1
// baseline (274.531 us; speedup 1.0000x reference)
//
#include <hip/hip_runtime.h>
#include <stdint.h>

#define N_EMBD 1024
#define N_HEADv 16
#define HEADv 64
#define Bv 2
#define Tv 2048
#define BT (Bv*Tv)      // 4096
#define C3 (3*N_EMBD)   // 3072

typedef __attribute__((ext_vector_type(8))) short bf16x8;
typedef __attribute__((ext_vector_type(4))) short bf16x4;
typedef __attribute__((ext_vector_type(4))) float f32x4;

__device__ __forceinline__ unsigned short f2bf(float f){
  union { float f; uint32_t u; } v; v.f = f;
  uint32_t u = v.u;
  uint32_t r = u + 0x7FFFu + ((u>>16)&1u);
  return (unsigned short)(r>>16);
}

// ---------------- fp32 -> bf16 elementwise ----------------
__global__ void k_cvt_bf16(const float* __restrict__ in, unsigned short* __restrict__ out, long n){
  long i = ((long)blockIdx.x*blockDim.x + threadIdx.x)*8;
  if(i >= n) return;
  float4 a = *reinterpret_cast<const float4*>(in+i);
  float4 b = *reinterpret_cast<const float4*>(in+i+4);
  union { int4 v; unsigned short s[8]; } o;
  o.s[0]=f2bf(a.x); o.s[1]=f2bf(a.y); o.s[2]=f2bf(a.z); o.s[3]=f2bf(a.w);
  o.s[4]=f2bf(b.x); o.s[5]=f2bf(b.y); o.s[6]=f2bf(b.z); o.s[7]=f2bf(b.w);
  *reinterpret_cast<int4*>(out+i) = o.v;
}

// ---------------- fp32 [K][N] -> bf16 [N][K] transpose ----------------
__global__ void k_transpose_bf16(const float* __restrict__ in, unsigned short* __restrict__ out, int K, int N){
  __shared__ float tile[64][65];
  int n0 = blockIdx.x*64, k0 = blockIdx.y*64;
  int t = threadIdx.x;
  #pragma unroll
  for(int p=0;p<4;p++){
    int row = (t>>4) + p*16;
    int col4 = (t&15)*4;
    float4 v = *reinterpret_cast<const float4*>(&in[(size_t)(k0+row)*N + n0 + col4]);
    tile[row][col4+0]=v.x; tile[row][col4+1]=v.y; tile[row][col4+2]=v.z; tile[row][col4+3]=v.w;
  }
  __syncthreads();
  #pragma unroll
  for(int p=0;p<4;p++){
    int nrow = (t>>4) + p*16;
    int kc = (t&15)*4;
    ushort4 o;
    o.x = f2bf(tile[kc+0][nrow]);
    o.y = f2bf(tile[kc+1][nrow]);
    o.z = f2bf(tile[kc+2][nrow]);
    o.w = f2bf(tile[kc+3][nrow]);
    *reinterpret_cast<ushort4*>(&out[(size_t)(n0+nrow)*K + k0 + kc]) = o;
  }
}

// ---------------- bf16 MFMA GEMM: C = A[M][K] @ Bt[N][K]^T + bias ----------------
// MODE 0: scatter to QKV [3][B][H][T][D] bf16.  MODE 1: fp32 out [M][N].
template<int MODE>
__global__ __launch_bounds__(256) void k_gemm(
    const unsigned short* __restrict__ A,
    const unsigned short* __restrict__ Bt,
    const float* __restrict__ bias,
    void* __restrict__ Cout,
    int M, int N, int K)
{
  const int BK=32;
  __shared__ unsigned short As[128][40];
  __shared__ unsigned short Bs[128][40];
  int m0 = blockIdx.y*128, n0 = blockIdx.x*128;
  int t = threadIdx.x, lane = t&63, wid = t>>6;
  int wm = (wid>>1)*64, wn = (wid&1)*64;
  int g = lane>>4, r16 = lane&15;
  f32x4 acc[4][4] = {};

  for(int k0=0;k0<K;k0+=BK){
    __syncthreads();
    #pragma unroll
    for(int it=0; it<2; ++it){
      int chunk = t + it*256;           // 0..511
      int row = chunk>>2, c8 = (chunk&3)*8;
      int4 va = *reinterpret_cast<const int4*>(&A [(size_t)(m0+row)*K + k0 + c8]);
      *reinterpret_cast<int4*>(&As[row][c8]) = va;
      int4 vb = *reinterpret_cast<const int4*>(&Bt[(size_t)(n0+row)*K + k0 + c8]);
      *reinterpret_cast<int4*>(&Bs[row][c8]) = vb;
    }
    __syncthreads();
    bf16x8 af[4], bfr[4];
    #pragma unroll
    for(int mi=0;mi<4;mi++) af[mi]  = *reinterpret_cast<const bf16x8*>(&As[wm+mi*16+r16][g*8]);
    #pragma unroll
    for(int ni=0;ni<4;ni++) bfr[ni] = *reinterpret_cast<const bf16x8*>(&Bs[wn+ni*16+r16][g*8]);
    #pragma unroll
    for(int mi=0;mi<4;mi++)
      #pragma unroll
      for(int ni=0;ni<4;ni++)
        acc[mi][ni] = __builtin_amdgcn_mfma_f32_16x16x32_bf16(af[mi], bfr[ni], acc[mi][ni], 0,0,0);
  }

  #pragma unroll
  for(int mi=0;mi<4;mi++){
    int mrow = m0+wm+mi*16;
    #pragma unroll
    for(int ni=0;ni<4;ni++){
      int ncol = n0+wn+ni*16 + r16;
      float bv = bias[ncol];
      #pragma unroll
      for(int reg=0;reg<4;reg++){
        int mm = mrow + g*4 + reg;      // C/D: col=lane&15, row=(lane>>4)*4+reg
        float val = acc[mi][ni][reg] + bv;
        if(MODE==0){
          int b = mm >> 11;             // /T
          int tt = mm & 2047;
          int which = ncol >> 10;       // q/k/v
          int cc = ncol & 1023;
          int h = cc >> 6, d = cc & 63;
          unsigned short* dst = (unsigned short*)Cout;
          size_t off = (size_t)which*BT*N_EMBD + ((((size_t)b*N_HEADv + h)*Tv + tt)*HEADv + d);
          dst[off] = f2bf(val);
        } else {
          ((float*)Cout)[(size_t)mm*N + ncol] = val;
        }
      }
    }
  }
}

// ---------------- flash attention (causal) ----------------
// QKV bf16 [3][B][H][T][D]; O bf16 [B*T][C] (heads concatenated)
__global__ __launch_bounds__(256) void k_attn(
    const unsigned short* __restrict__ QKV,
    unsigned short* __restrict__ O)
{
  const int KP = 72;   // K / P row pad (bf16 elems), 16B-aligned rows
  const int VP = 68;   // Vt row pad, 8B-aligned rows (b64 reads)
  __shared__ unsigned short Ks[64][KP];
  __shared__ unsigned short Vt[64][VP];   // Vt[d][key]
  __shared__ unsigned short Ps[4][16][KP];
  int blk = blockIdx.x;
  int qt = blk & 31;            // T/64 = 32 q-tiles
  int bh = blk >> 5;            // b*H + h
  int t = threadIdx.x, lane=t&63, wid=t>>6;
  int g = lane>>4, r16 = lane&15;
  const size_t headoff = (size_t)bh*Tv*HEADv;
  const unsigned short* Qp = QKV + headoff;
  const unsigned short* Kp = QKV + (size_t)BT*N_EMBD + headoff;
  const unsigned short* Vp = QKV + 2*(size_t)BT*N_EMBD + headoff;
  int q0 = qt*64 + wid*16;

  bf16x8 aq[2];
  #pragma unroll
  for(int kb=0;kb<2;kb++)
    aq[kb] = *reinterpret_cast<const bf16x8*>(&Qp[(size_t)(q0+r16)*HEADv + kb*32 + g*8]);

  f32x4 oacc[4] = {};
  float mrun[4], lrun[4];
  #pragma unroll
  for(int i=0;i<4;i++){ mrun[i]=-1e30f; lrun[i]=0.f; }

  int nkt = qt+1;
  for(int kt=0; kt<nkt; ++kt){
    __syncthreads();
    #pragma unroll
    for(int it=0; it<2; ++it){
      int chunk = t + it*256;          // 0..511
      int r = chunk>>3, c8 = (chunk&7)*8;
      int4 kv = *reinterpret_cast<const int4*>(&Kp[(size_t)(kt*64+r)*HEADv + c8]);
      *reinterpret_cast<int4*>(&Ks[r][c8]) = kv;
      int4 vv = *reinterpret_cast<const int4*>(&Vp[(size_t)(kt*64+r)*HEADv + c8]);
      union { int4 v; unsigned short s[8]; } uv; uv.v = vv;
      #pragma unroll
      for(int j=0;j<8;j++) Vt[c8+j][r] = uv.s[j];
    }
    __syncthreads();

    // S = Q K^T  (A row = q = lane&15 on A side; D: col=key low4, row=q)
    f32x4 sacc[4];
    #pragma unroll
    for(int nb=0;nb<4;nb++){
      sacc[nb] = (f32x4){0.f,0.f,0.f,0.f};
      #pragma unroll
      for(int kb=0;kb<2;kb++){
        bf16x8 bk = *reinterpret_cast<const bf16x8*>(&Ks[nb*16+r16][kb*32+g*8]);
        sacc[nb] = __builtin_amdgcn_mfma_f32_16x16x32_bf16(aq[kb], bk, sacc[nb],0,0,0);
      }
    }

    bool diag = (kt == qt);
    float pv[4][4];
    #pragma unroll
    for(int nb=0;nb<4;nb++)
      #pragma unroll
      for(int reg=0;reg<4;reg++){
        float s = sacc[nb][reg] * 0.125f;
        if(diag){
          int qrow = qt*64 + wid*16 + g*4 + reg;
          int key  = kt*64 + nb*16 + r16;
          if(key > qrow) s = -1e30f;
        }
        pv[nb][reg] = s;
      }

    float alpha[4];
    #pragma unroll
    for(int reg=0;reg<4;reg++){
      float m_ = fmaxf(fmaxf(pv[0][reg],pv[1][reg]),fmaxf(pv[2][reg],pv[3][reg]));
      #pragma unroll
      for(int sh=1; sh<16; sh<<=1) m_ = fmaxf(m_, __shfl_xor(m_, sh, 64));
      float mn = fmaxf(mrun[reg], m_);
      alpha[reg] = __expf(mrun[reg]-mn);
      mrun[reg] = mn;
    }
    float rsum[4] = {0.f,0.f,0.f,0.f};
    #pragma unroll
    for(int nb=0;nb<4;nb++)
      #pragma unroll
      for(int reg=0;reg<4;reg++){
        float p = __expf(pv[nb][reg]-mrun[reg]);
        pv[nb][reg]=p;
        rsum[reg]+=p;
      }
    #pragma unroll
    for(int reg=0;reg<4;reg++){
      #pragma unroll
      for(int sh=1; sh<16; sh<<=1) rsum[reg] += __shfl_xor(rsum[reg], sh, 64);
      lrun[reg] = lrun[reg]*alpha[reg] + rsum[reg];
    }
    #pragma unroll
    for(int nb=0;nb<4;nb++)
      #pragma unroll
      for(int reg=0;reg<4;reg++)
        Ps[wid][g*4+reg][nb*16+r16] = f2bf(pv[nb][reg]);
    #pragma unroll
    for(int nb=0;nb<4;nb++)
      #pragma unroll
      for(int reg=0;reg<4;reg++)
        oacc[nb][reg] *= alpha[reg];

    // PV: A = P (row=q=lane&15), B = V via Vt[d][key]
    #pragma unroll
    for(int kb=0;kb<2;kb++){
      bf16x8 ap = *reinterpret_cast<const bf16x8*>(&Ps[wid][r16][kb*32+g*8]);
      #pragma unroll
      for(int nb=0;nb<4;nb++){
        bf16x4 lo = *reinterpret_cast<const bf16x4*>(&Vt[nb*16+r16][kb*32+g*8]);
        bf16x4 hi = *reinterpret_cast<const bf16x4*>(&Vt[nb*16+r16][kb*32+g*8+4]);
        bf16x8 bv = __builtin_shufflevector(lo, hi, 0,1,2,3,4,5,6,7);
        oacc[nb] = __builtin_amdgcn_mfma_f32_16x16x32_bf16(ap, bv, oacc[nb],0,0,0);
      }
    }
  }

  int b = bh >> 4, h = bh & 15;
  #pragma unroll
  for(int nb=0;nb<4;nb++){
    #pragma unroll
    for(int reg=0;reg<4;reg++){
      int tok = qt*64 + wid*16 + g*4 + reg;
      size_t row = (size_t)b*Tv + tok;
      int col = h*HEADv + nb*16 + r16;
      O[row*N_EMBD + col] = f2bf(oacc[nb][reg] / lrun[reg]);
    }
  }
}

extern "C" void kernel_launch(void* const* d_in, const int* in_sizes, int n_in,
                              void* d_out, int out_size, void* d_ws, size_t ws_size,
                              hipStream_t stream){
  const float* x      = (const float*)d_in[0];
  const float* w_attn = (const float*)d_in[1];
  const float* b_attn = (const float*)d_in[2];
  const float* w_proj = (const float*)d_in[3];
  const float* b_proj = (const float*)d_in[4];
  char* ws = (char*)d_ws;
  unsigned short* xb  = (unsigned short*)ws;                        // 8 MB
  unsigned short* qkv = (unsigned short*)(ws + 8ll*1024*1024);      // 24 MB
  unsigned short* ob  = (unsigned short*)(ws + 32ll*1024*1024);     // 8 MB
  unsigned short* wat = (unsigned short*)(ws + 40ll*1024*1024);     // 6 MB
  unsigned short* wpt = (unsigned short*)(ws + 46ll*1024*1024);     // 2 MB

  k_cvt_bf16<<<2048,256,0,stream>>>(x, xb, (long)BT*N_EMBD);
  k_transpose_bf16<<<dim3(C3/64, N_EMBD/64),256,0,stream>>>(w_attn, wat, N_EMBD, C3);
  k_transpose_bf16<<<dim3(N_EMBD/64, N_EMBD/64),256,0,stream>>>(w_proj, wpt, N_EMBD, N_EMBD);
  k_gemm<0><<<dim3(C3/128, BT/128),256,0,stream>>>(xb, wat, b_attn, (void*)qkv, BT, C3, N_EMBD);
  k_attn<<<dim3(Bv*N_HEADv*(Tv/64)),256,0,stream>>>(qkv, ob);
  k_gemm<1><<<dim3(N_EMBD/128, BT/128),256,0,stream>>>(ob, wpt, b_proj, d_out, BT, N_EMBD, N_EMBD);
}

// Round 2
// 213.611 us; speedup vs baseline: 1.2852x; 1.2852x over previous
//
#include <hip/hip_runtime.h>
#include <stdint.h>

#define N_EMBD 1024
#define N_HEADv 16
#define HEADv 64
#define Bv 2
#define Tv 2048
#define BT (Bv*Tv)      // 4096
#define C3 (3*N_EMBD)   // 3072

typedef __attribute__((ext_vector_type(8))) short bf16x8;
typedef __attribute__((ext_vector_type(4))) float f32x4;

__device__ __forceinline__ unsigned short f2bf(float f){
  union { float f; uint32_t u; } v; v.f = f;
  uint32_t u = v.u;
  uint32_t r = u + 0x7FFFu + ((u>>16)&1u);
  return (unsigned short)(r>>16);
}

// ---------------- fp32 -> bf16 elementwise ----------------
__global__ void k_cvt_bf16(const float* __restrict__ in, unsigned short* __restrict__ out, long n){
  long i = ((long)blockIdx.x*blockDim.x + threadIdx.x)*8;
  if(i >= n) return;
  float4 a = *reinterpret_cast<const float4*>(in+i);
  float4 b = *reinterpret_cast<const float4*>(in+i+4);
  union { int4 v; unsigned short s[8]; } o;
  o.s[0]=f2bf(a.x); o.s[1]=f2bf(a.y); o.s[2]=f2bf(a.z); o.s[3]=f2bf(a.w);
  o.s[4]=f2bf(b.x); o.s[5]=f2bf(b.y); o.s[6]=f2bf(b.z); o.s[7]=f2bf(b.w);
  *reinterpret_cast<int4*>(out+i) = o.v;
}

// ---------------- fp32 [K][N] -> bf16 [N][K] transpose ----------------
__global__ void k_transpose_bf16(const float* __restrict__ in, unsigned short* __restrict__ out, int K, int N){
  __shared__ float tile[64][65];
  int n0 = blockIdx.x*64, k0 = blockIdx.y*64;
  int t = threadIdx.x;
  #pragma unroll
  for(int p=0;p<4;p++){
    int row = (t>>4) + p*16;
    int col4 = (t&15)*4;
    float4 v = *reinterpret_cast<const float4*>(&in[(size_t)(k0+row)*N + n0 + col4]);
    tile[row][col4+0]=v.x; tile[row][col4+1]=v.y; tile[row][col4+2]=v.z; tile[row][col4+3]=v.w;
  }
  __syncthreads();
  #pragma unroll
  for(int p=0;p<4;p++){
    int nrow = (t>>4) + p*16;
    int kc = (t&15)*4;
    ushort4 o;
    o.x = f2bf(tile[kc+0][nrow]);
    o.y = f2bf(tile[kc+1][nrow]);
    o.z = f2bf(tile[kc+2][nrow]);
    o.w = f2bf(tile[kc+3][nrow]);
    *reinterpret_cast<ushort4*>(&out[(size_t)(n0+nrow)*K + k0 + kc]) = o;
  }
}

// ---------------- bf16 [b,h,t,d] -> bf16 [b,h,d,t] (V transpose) ----------------
__global__ __launch_bounds__(256) void k_transpose_v(const unsigned short* __restrict__ in,
                                                     unsigned short* __restrict__ out){
  __shared__ unsigned short tile[64][68];
  int bh = blockIdx.x >> 5;
  int t0 = (blockIdx.x & 31) * 64;
  const unsigned short* src = in  + (size_t)bh*Tv*HEADv;
  unsigned short*       dst = out + (size_t)bh*HEADv*Tv;
  int t = threadIdx.x;
  #pragma unroll
  for(int it=0; it<2; ++it){
    int chunk = t + it*256;        // 0..511
    int r = chunk>>3, c8 = (chunk&7)*8;     // r = token row, c8 = d col
    *reinterpret_cast<int4*>(&tile[r][c8]) =
      *reinterpret_cast<const int4*>(&src[(size_t)(t0+r)*HEADv + c8]);
  }
  __syncthreads();
  #pragma unroll
  for(int it=0; it<2; ++it){
    int chunk = t + it*256;
    int r = chunk>>3, c8 = (chunk&7)*8;     // r = d row, c8 = token col
    union { int4 v; unsigned short s[8]; } o;
    #pragma unroll
    for(int j=0;j<8;j++) o.s[j] = tile[c8+j][r];
    *reinterpret_cast<int4*>(&dst[(size_t)r*Tv + t0 + c8]) = o.v;
  }
}

// ---------------- bf16 MFMA GEMM: C = A[M][K] @ Bt[N][K]^T + bias ----------------
// MODE 0: scatter to QKV [3][B][H][T][D] bf16.  MODE 1: fp32 out [M][N].
template<int MODE>
__global__ __launch_bounds__(256) void k_gemm(
    const unsigned short* __restrict__ A,
    const unsigned short* __restrict__ Bt,
    const float* __restrict__ bias,
    void* __restrict__ Cout,
    int M, int N, int K)
{
  const int BK=32;
  __shared__ unsigned short As[128][40];
  __shared__ unsigned short Bs[128][40];
  int m0 = blockIdx.y*128, n0 = blockIdx.x*128;
  int t = threadIdx.x, lane = t&63, wid = t>>6;
  int wm = (wid>>1)*64, wn = (wid&1)*64;
  int g = lane>>4, r16 = lane&15;
  f32x4 acc[4][4] = {};

  for(int k0=0;k0<K;k0+=BK){
    __syncthreads();
    #pragma unroll
    for(int it=0; it<2; ++it){
      int chunk = t + it*256;           // 0..511
      int row = chunk>>2, c8 = (chunk&3)*8;
      int4 va = *reinterpret_cast<const int4*>(&A [(size_t)(m0+row)*K + k0 + c8]);
      *reinterpret_cast<int4*>(&As[row][c8]) = va;
      int4 vb = *reinterpret_cast<const int4*>(&Bt[(size_t)(n0+row)*K + k0 + c8]);
      *reinterpret_cast<int4*>(&Bs[row][c8]) = vb;
    }
    __syncthreads();
    bf16x8 af[4], bfr[4];
    #pragma unroll
    for(int mi=0;mi<4;mi++) af[mi]  = *reinterpret_cast<const bf16x8*>(&As[wm+mi*16+r16][g*8]);
    #pragma unroll
    for(int ni=0;ni<4;ni++) bfr[ni] = *reinterpret_cast<const bf16x8*>(&Bs[wn+ni*16+r16][g*8]);
    #pragma unroll
    for(int mi=0;mi<4;mi++)
      #pragma unroll
      for(int ni=0;ni<4;ni++)
        acc[mi][ni] = __builtin_amdgcn_mfma_f32_16x16x32_bf16(af[mi], bfr[ni], acc[mi][ni], 0,0,0);
  }

  #pragma unroll
  for(int mi=0;mi<4;mi++){
    int mrow = m0+wm+mi*16;
    #pragma unroll
    for(int ni=0;ni<4;ni++){
      int ncol = n0+wn+ni*16 + r16;
      float bv = bias[ncol];
      #pragma unroll
      for(int reg=0;reg<4;reg++){
        int mm = mrow + g*4 + reg;      // C/D: col=lane&15, row=(lane>>4)*4+reg
        float val = acc[mi][ni][reg] + bv;
        if(MODE==0){
          int b = mm >> 11;             // /T
          int tt = mm & 2047;
          int which = ncol >> 10;       // q/k/v
          int cc = ncol & 1023;
          int h = cc >> 6, d = cc & 63;
          unsigned short* dst = (unsigned short*)Cout;
          size_t off = (size_t)which*BT*N_EMBD + ((((size_t)b*N_HEADv + h)*Tv + tt)*HEADv + d);
          dst[off] = f2bf(val);
        } else {
          ((float*)Cout)[(size_t)mm*N + ncol] = val;
        }
      }
    }
  }
}

// ---------------- flash attention (causal) ----------------
// Q,K bf16 [B,H,T,D] (inside QKV); Vt bf16 [B,H,D,T]; O bf16 [B*T][C]
__global__ __launch_bounds__(256) void k_attn(
    const unsigned short* __restrict__ QKV,
    const unsigned short* __restrict__ VT,
    unsigned short* __restrict__ O)
{
  const int KP = 72;   // row pad (bf16 elems): rows 144B apart -> 2 lanes/bank on b128 reads (free)
  __shared__ unsigned short Ks[64][KP];   // Ks[key][d]
  __shared__ unsigned short Vs[64][KP];   // Vs[d][key]   (from VT, no in-loop transpose)
  __shared__ unsigned short Ps[4][16][KP];
  int blk = blockIdx.x;
  int qt = 31 - (blk & 31);     // longest blocks first
  int bh = blk >> 5;            // b*H + h
  int t = threadIdx.x, lane=t&63, wid=t>>6;
  int g = lane>>4, r16 = lane&15;
  const size_t headoff = (size_t)bh*Tv*HEADv;
  const unsigned short* Qp  = QKV + headoff;
  const unsigned short* Kp  = QKV + (size_t)BT*N_EMBD + headoff;
  const unsigned short* Vtp = VT + (size_t)bh*HEADv*Tv;
  int q0 = qt*64 + wid*16;

  bf16x8 aq[2];
  #pragma unroll
  for(int kb=0;kb<2;kb++)
    aq[kb] = *reinterpret_cast<const bf16x8*>(&Qp[(size_t)(q0+r16)*HEADv + kb*32 + g*8]);

  f32x4 oacc[4] = {};
  float mrun[4], lrun[4];
  #pragma unroll
  for(int i=0;i<4;i++){ mrun[i]=-1e30f; lrun[i]=0.f; }

  const int nkt = qt+1;
  // staging chunk mapping (per thread, 2 chunks each for K and Vt)
  int r_[2], c_[2];
  #pragma unroll
  for(int it=0;it<2;it++){ int chunk = t + it*256; r_[it]=chunk>>3; c_[it]=(chunk&7)*8; }

  // prologue: load tile 0 into regs
  int4 kc0, kc1, vc0, vc1;
  kc0 = *reinterpret_cast<const int4*>(&Kp [(size_t)(r_[0])*HEADv + c_[0]]);
  kc1 = *reinterpret_cast<const int4*>(&Kp [(size_t)(r_[1])*HEADv + c_[1]]);
  vc0 = *reinterpret_cast<const int4*>(&Vtp[(size_t)(r_[0])*Tv + c_[0]]);
  vc1 = *reinterpret_cast<const int4*>(&Vtp[(size_t)(r_[1])*Tv + c_[1]]);

  for(int kt=0; kt<nkt; ++kt){
    // write current tile to LDS (vmcnt wait inserted by compiler)
    *reinterpret_cast<int4*>(&Ks[r_[0]][c_[0]]) = kc0;
    *reinterpret_cast<int4*>(&Ks[r_[1]][c_[1]]) = kc1;
    *reinterpret_cast<int4*>(&Vs[r_[0]][c_[0]]) = vc0;
    *reinterpret_cast<int4*>(&Vs[r_[1]][c_[1]]) = vc1;
    // issue next tile's loads -> latency hides under compute (T14)
    int4 kn0, kn1, vn0, vn1;
    if(kt+1 < nkt){
      kn0 = *reinterpret_cast<const int4*>(&Kp [(size_t)((kt+1)*64 + r_[0])*HEADv + c_[0]]);
      kn1 = *reinterpret_cast<const int4*>(&Kp [(size_t)((kt+1)*64 + r_[1])*HEADv + c_[1]]);
      vn0 = *reinterpret_cast<const int4*>(&Vtp[(size_t)(r_[0])*Tv + (kt+1)*64 + c_[0]]);
      vn1 = *reinterpret_cast<const int4*>(&Vtp[(size_t)(r_[1])*Tv + (kt+1)*64 + c_[1]]);
    }
    __syncthreads();

    // S = Q K^T  (D: col=key=r16, row=q=g*4+reg within 16x16)
    f32x4 sacc[4];
    #pragma unroll
    for(int nb=0;nb<4;nb++){
      sacc[nb] = (f32x4){0.f,0.f,0.f,0.f};
      #pragma unroll
      for(int kb=0;kb<2;kb++){
        bf16x8 bk = *reinterpret_cast<const bf16x8*>(&Ks[nb*16+r16][kb*32+g*8]);
        sacc[nb] = __builtin_amdgcn_mfma_f32_16x16x32_bf16(aq[kb], bk, sacc[nb],0,0,0);
      }
    }

    bool diag = (kt == qt);
    float pv[4][4];
    #pragma unroll
    for(int nb=0;nb<4;nb++)
      #pragma unroll
      for(int reg=0;reg<4;reg++){
        float s = sacc[nb][reg] * 0.125f;
        if(diag){
          int qrow = q0 + g*4 + reg;
          int key  = kt*64 + nb*16 + r16;
          if(key > qrow) s = -1e30f;
        }
        pv[nb][reg] = s;
      }

    float alpha[4];
    #pragma unroll
    for(int reg=0;reg<4;reg++){
      float m_ = fmaxf(fmaxf(pv[0][reg],pv[1][reg]),fmaxf(pv[2][reg],pv[3][reg]));
      #pragma unroll
      for(int sh=1; sh<16; sh<<=1) m_ = fmaxf(m_, __shfl_xor(m_, sh, 64));
      float mn = fmaxf(mrun[reg], m_);
      alpha[reg] = __expf(mrun[reg]-mn);
      mrun[reg] = mn;
    }
    float rsum[4] = {0.f,0.f,0.f,0.f};
    #pragma unroll
    for(int nb=0;nb<4;nb++)
      #pragma unroll
      for(int reg=0;reg<4;reg++){
        float p = __expf(pv[nb][reg]-mrun[reg]);
        pv[nb][reg]=p;
        rsum[reg]+=p;
      }
    #pragma unroll
    for(int reg=0;reg<4;reg++){
      #pragma unroll
      for(int sh=1; sh<16; sh<<=1) rsum[reg] += __shfl_xor(rsum[reg], sh, 64);
      lrun[reg] = lrun[reg]*alpha[reg] + rsum[reg];
    }
    #pragma unroll
    for(int nb=0;nb<4;nb++)
      #pragma unroll
      for(int reg=0;reg<4;reg++)
        Ps[wid][g*4+reg][nb*16+r16] = f2bf(pv[nb][reg]);
    #pragma unroll
    for(int nb=0;nb<4;nb++)
      #pragma unroll
      for(int reg=0;reg<4;reg++)
        oacc[nb][reg] *= alpha[reg];

    // PV: A = P (row=q), B = V[key][d] read from Vs[d][key] as 16B rows
    #pragma unroll
    for(int kb=0;kb<2;kb++){
      bf16x8 ap = *reinterpret_cast<const bf16x8*>(&Ps[wid][r16][kb*32+g*8]);
      #pragma unroll
      for(int nb=0;nb<4;nb++){
        bf16x8 bv = *reinterpret_cast<const bf16x8*>(&Vs[nb*16+r16][kb*32+g*8]);
        oacc[nb] = __builtin_amdgcn_mfma_f32_16x16x32_bf16(ap, bv, oacc[nb],0,0,0);
      }
    }
    __syncthreads();
    if(kt+1 < nkt){ kc0=kn0; kc1=kn1; vc0=vn0; vc1=vn1; }
  }

  int b = bh >> 4, h = bh & 15;
  float rinv[4];
  #pragma unroll
  for(int reg=0;reg<4;reg++) rinv[reg] = 1.0f / lrun[reg];
  #pragma unroll
  for(int nb=0;nb<4;nb++){
    #pragma unroll
    for(int reg=0;reg<4;reg++){
      int tok = q0 + g*4 + reg;
      size_t row = (size_t)b*Tv + tok;
      int col = h*HEADv + nb*16 + r16;
      O[row*N_EMBD + col] = f2bf(oacc[nb][reg] * rinv[reg]);
    }
  }
}

extern "C" void kernel_launch(void* const* d_in, const int* in_sizes, int n_in,
                              void* d_out, int out_size, void* d_ws, size_t ws_size,
                              hipStream_t stream){
  const float* x      = (const float*)d_in[0];
  const float* w_attn = (const float*)d_in[1];
  const float* b_attn = (const float*)d_in[2];
  const float* w_proj = (const float*)d_in[3];
  const float* b_proj = (const float*)d_in[4];
  char* ws = (char*)d_ws;
  unsigned short* xb  = (unsigned short*)ws;                        // 8 MB (reused as Vt after QKV GEMM)
  unsigned short* qkv = (unsigned short*)(ws + 8ll*1024*1024);      // 24 MB
  unsigned short* ob  = (unsigned short*)(ws + 32ll*1024*1024);     // 8 MB
  unsigned short* wat = (unsigned short*)(ws + 40ll*1024*1024);     // 6 MB
  unsigned short* wpt = (unsigned short*)(ws + 46ll*1024*1024);     // 2 MB
  unsigned short* vt  = xb;                                         // alias: xb dead after QKV GEMM

  k_cvt_bf16<<<2048,256,0,stream>>>(x, xb, (long)BT*N_EMBD);
  k_transpose_bf16<<<dim3(C3/64, N_EMBD/64),256,0,stream>>>(w_attn, wat, N_EMBD, C3);
  k_transpose_bf16<<<dim3(N_EMBD/64, N_EMBD/64),256,0,stream>>>(w_proj, wpt, N_EMBD, N_EMBD);
  k_gemm<0><<<dim3(C3/128, BT/128),256,0,stream>>>(xb, wat, b_attn, (void*)qkv, BT, C3, N_EMBD);
  k_transpose_v<<<dim3(Bv*N_HEADv*(Tv/64)),256,0,stream>>>(qkv + 2ll*BT*N_EMBD, vt);
  k_attn<<<dim3(Bv*N_HEADv*(Tv/64)),256,0,stream>>>(qkv, vt, ob);
  k_gemm<1><<<dim3(N_EMBD/128, BT/128),256,0,stream>>>(ob, wpt, b_proj, d_out, BT, N_EMBD, N_EMBD);
}

// Round 3
// 170.634 us; speedup vs baseline: 1.6089x; 1.2519x over previous
//
#include <hip/hip_runtime.h>
#include <stdint.h>

#define N_EMBD 1024
#define N_HEADv 16
#define HEADv 64
#define Bv 2
#define Tv 2048
#define BT (Bv*Tv)      // 4096
#define C3 (3*N_EMBD)   // 3072

typedef __attribute__((ext_vector_type(8))) short bf16x8;
typedef __attribute__((ext_vector_type(4))) float f32x4;

typedef __attribute__((address_space(3))) uint32_t lds_u32;
typedef const __attribute__((address_space(1))) uint32_t glb_u32;

__device__ __forceinline__ void gload_lds16(const void* g, void* l){
  __builtin_amdgcn_global_load_lds((glb_u32*)g, (lds_u32*)l, 16, 0, 0);
}

__device__ __forceinline__ unsigned short f2bf(float f){
  union { float f; uint32_t u; } v; v.f = f;
  uint32_t u = v.u;
  uint32_t r = u + 0x7FFFu + ((u>>16)&1u);
  return (unsigned short)(r>>16);
}
// fast round (no RNE tie-break): used for P (feeds bf16 MFMA anyway)
__device__ __forceinline__ uint32_t f2bf_fast(float f){
  union { float f; uint32_t u; } v; v.f = f;
  return (v.u + 0x8000u) >> 16;
}

// ---------------- fp32 -> bf16 elementwise ----------------
__global__ void k_cvt_bf16(const float* __restrict__ in, unsigned short* __restrict__ out, long n){
  long i = ((long)blockIdx.x*blockDim.x + threadIdx.x)*8;
  if(i >= n) return;
  float4 a = *reinterpret_cast<const float4*>(in+i);
  float4 b = *reinterpret_cast<const float4*>(in+i+4);
  union { int4 v; unsigned short s[8]; } o;
  o.s[0]=f2bf(a.x); o.s[1]=f2bf(a.y); o.s[2]=f2bf(a.z); o.s[3]=f2bf(a.w);
  o.s[4]=f2bf(b.x); o.s[5]=f2bf(b.y); o.s[6]=f2bf(b.z); o.s[7]=f2bf(b.w);
  *reinterpret_cast<int4*>(out+i) = o.v;
}

// ---------------- fp32 [K][N] -> bf16 [N][K] transpose ----------------
__global__ void k_transpose_bf16(const float* __restrict__ in, unsigned short* __restrict__ out, int K, int N){
  __shared__ float tile[64][65];
  int n0 = blockIdx.x*64, k0 = blockIdx.y*64;
  int t = threadIdx.x;
  #pragma unroll
  for(int p=0;p<4;p++){
    int row = (t>>4) + p*16;
    int col4 = (t&15)*4;
    float4 v = *reinterpret_cast<const float4*>(&in[(size_t)(k0+row)*N + n0 + col4]);
    tile[row][col4+0]=v.x; tile[row][col4+1]=v.y; tile[row][col4+2]=v.z; tile[row][col4+3]=v.w;
  }
  __syncthreads();
  #pragma unroll
  for(int p=0;p<4;p++){
    int nrow = (t>>4) + p*16;
    int kc = (t&15)*4;
    ushort4 o;
    o.x = f2bf(tile[kc+0][nrow]);
    o.y = f2bf(tile[kc+1][nrow]);
    o.z = f2bf(tile[kc+2][nrow]);
    o.w = f2bf(tile[kc+3][nrow]);
    *reinterpret_cast<ushort4*>(&out[(size_t)(n0+nrow)*K + k0 + kc]) = o;
  }
}

// ---------------- bf16 [b,h,t,d] -> bf16 [b,h,d,t] (V transpose) ----------------
__global__ __launch_bounds__(256) void k_transpose_v(const unsigned short* __restrict__ in,
                                                     unsigned short* __restrict__ out){
  __shared__ unsigned short tile[64][68];
  int bh = blockIdx.x >> 5;
  int t0 = (blockIdx.x & 31) * 64;
  const unsigned short* src = in  + (size_t)bh*Tv*HEADv;
  unsigned short*       dst = out + (size_t)bh*HEADv*Tv;
  int t = threadIdx.x;
  #pragma unroll
  for(int it=0; it<2; ++it){
    int chunk = t + it*256;        // 0..511
    int r = chunk>>3, c8 = (chunk&7)*8;     // r = token row, c8 = d col
    *reinterpret_cast<int4*>(&tile[r][c8]) =
      *reinterpret_cast<const int4*>(&src[(size_t)(t0+r)*HEADv + c8]);
  }
  __syncthreads();
  #pragma unroll
  for(int it=0; it<2; ++it){
    int chunk = t + it*256;
    int r = chunk>>3, c8 = (chunk&7)*8;     // r = d row, c8 = token col
    union { int4 v; unsigned short s[8]; } o;
    #pragma unroll
    for(int j=0;j<8;j++) o.s[j] = tile[c8+j][r];
    *reinterpret_cast<int4*>(&dst[(size_t)r*Tv + t0 + c8]) = o.v;
  }
}

// ---------------- bf16 MFMA GEMM: C = A[M][K] @ Bt[N][K]^T + bias ----------------
// global_load_lds width-16 staging, linear LDS tiles (m97 structure).
// MODE 0: scatter to QKV [3][B][H][T][D] bf16.  MODE 1: fp32 out [M][N].
template<int MODE>
__global__ __launch_bounds__(256) void k_gemm(
    const unsigned short* __restrict__ A,
    const unsigned short* __restrict__ Bt,
    const float* __restrict__ bias,
    void* __restrict__ Cout,
    int M, int N, int K)
{
  const int BK=32;
  __shared__ unsigned short As[128*BK];   // linear [row][32], 64B rows (no pad: gload_lds)
  __shared__ unsigned short Bs[128*BK];
  int m0 = blockIdx.y*128, n0 = blockIdx.x*128;
  int t = threadIdx.x, lane = t&63, wid = t>>6;
  int wm = (wid>>1)*64, wn = (wid&1)*64;
  int g = lane>>4, r16 = lane&15;
  int rl = lane>>2, cl = (lane&3)*8;      // staging: lane -> (row, col8)
  f32x4 acc[4][4] = {};

  for(int k0=0;k0<K;k0+=BK){
    __syncthreads();
    #pragma unroll
    for(int i=0;i<2;i++){
      int rbase = wid*16 + i*64;
      gload_lds16(&A [(size_t)(m0+rbase+rl)*K + k0 + cl], &As[rbase*BK]);
      gload_lds16(&Bt[(size_t)(n0+rbase+rl)*K + k0 + cl], &Bs[rbase*BK]);
    }
    __syncthreads();
    bf16x8 af[4], bfr[4];
    #pragma unroll
    for(int mi=0;mi<4;mi++) af[mi]  = *reinterpret_cast<const bf16x8*>(&As[(wm+mi*16+r16)*BK + g*8]);
    #pragma unroll
    for(int ni=0;ni<4;ni++) bfr[ni] = *reinterpret_cast<const bf16x8*>(&Bs[(wn+ni*16+r16)*BK + g*8]);
    #pragma unroll
    for(int mi=0;mi<4;mi++)
      #pragma unroll
      for(int ni=0;ni<4;ni++)
        acc[mi][ni] = __builtin_amdgcn_mfma_f32_16x16x32_bf16(af[mi], bfr[ni], acc[mi][ni], 0,0,0);
  }

  #pragma unroll
  for(int mi=0;mi<4;mi++){
    int mrow = m0+wm+mi*16;
    #pragma unroll
    for(int ni=0;ni<4;ni++){
      int ncol = n0+wn+ni*16 + r16;
      float bv = bias[ncol];
      #pragma unroll
      for(int reg=0;reg<4;reg++){
        int mm = mrow + g*4 + reg;      // C/D: col=lane&15, row=(lane>>4)*4+reg
        float val = acc[mi][ni][reg] + bv;
        if(MODE==0){
          int b = mm >> 11;             // /T
          int tt = mm & 2047;
          int which = ncol >> 10;       // q/k/v
          int cc = ncol & 1023;
          int h = cc >> 6, d = cc & 63;
          unsigned short* dst = (unsigned short*)Cout;
          size_t off = (size_t)which*BT*N_EMBD + ((((size_t)b*N_HEADv + h)*Tv + tt)*HEADv + d);
          dst[off] = f2bf(val);
        } else {
          ((float*)Cout)[(size_t)mm*N + ncol] = val;
        }
      }
    }
  }
}

// ---------------- flash attention (causal), swapped-operand form ----------------
// Q,K bf16 [B,H,T,D] (inside QKV); Vt bf16 [B,H,D,T]; O bf16 [B*T][C]
// S^T = mfma(K,Q): lane holds S[q=q0+r16][key=nb*16+g*4+reg] -> per-lane scalar stats.
// O^T = mfma(Vt,P): lane holds O[q=q0+r16][d=nb*16+g*4+reg].
__global__ __launch_bounds__(256) void k_attn(
    const unsigned short* __restrict__ QKV,
    const unsigned short* __restrict__ VT,
    unsigned short* __restrict__ O)
{
  const int KP = 72;   // 144B row stride
  __shared__ unsigned short Ks[64][KP];   // Ks[key][d]
  __shared__ unsigned short Vs[64][KP];   // Vs[d][key]
  __shared__ unsigned short Ps[4][16][KP];// Ps[wave][q][key]
  int blk = blockIdx.x;
  int qt = 31 - (blk & 31);     // longest blocks first
  int bh = blk >> 5;            // b*H + h
  int t = threadIdx.x, lane=t&63, wid=t>>6;
  int g = lane>>4, r16 = lane&15;
  const size_t headoff = (size_t)bh*Tv*HEADv;
  const unsigned short* Qp  = QKV + headoff;
  const unsigned short* Kp  = QKV + (size_t)BT*N_EMBD + headoff;
  const unsigned short* Vtp = VT + (size_t)bh*HEADv*Tv;
  int q0 = qt*64 + wid*16;

  bf16x8 aq[2];   // B-operand: col = q = r16
  #pragma unroll
  for(int kb=0;kb<2;kb++)
    aq[kb] = *reinterpret_cast<const bf16x8*>(&Qp[(size_t)(q0+r16)*HEADv + kb*32 + g*8]);

  f32x4 oacc[4] = {};          // oacc[nb][reg] = O[q=q0+r16][d=nb*16+g*4+reg]
  float m2 = -1e30f, l = 0.f;  // per-lane scalar stats (log2 domain)

  const int nkt = qt+1;
  int r_[2], c_[2];
  #pragma unroll
  for(int it=0;it<2;it++){ int chunk = t + it*256; r_[it]=chunk>>3; c_[it]=(chunk&7)*8; }

  // prologue: load tile 0 into regs (T14: issue-early, write-late)
  int4 kc0, kc1, vc0, vc1;
  kc0 = *reinterpret_cast<const int4*>(&Kp [(size_t)(r_[0])*HEADv + c_[0]]);
  kc1 = *reinterpret_cast<const int4*>(&Kp [(size_t)(r_[1])*HEADv + c_[1]]);
  vc0 = *reinterpret_cast<const int4*>(&Vtp[(size_t)(r_[0])*Tv + c_[0]]);
  vc1 = *reinterpret_cast<const int4*>(&Vtp[(size_t)(r_[1])*Tv + c_[1]]);

  for(int kt=0; kt<nkt; ++kt){
    *reinterpret_cast<int4*>(&Ks[r_[0]][c_[0]]) = kc0;
    *reinterpret_cast<int4*>(&Ks[r_[1]][c_[1]]) = kc1;
    *reinterpret_cast<int4*>(&Vs[r_[0]][c_[0]]) = vc0;
    *reinterpret_cast<int4*>(&Vs[r_[1]][c_[1]]) = vc1;
    int4 kn0, kn1, vn0, vn1;
    if(kt+1 < nkt){
      kn0 = *reinterpret_cast<const int4*>(&Kp [(size_t)((kt+1)*64 + r_[0])*HEADv + c_[0]]);
      kn1 = *reinterpret_cast<const int4*>(&Kp [(size_t)((kt+1)*64 + r_[1])*HEADv + c_[1]]);
      vn0 = *reinterpret_cast<const int4*>(&Vtp[(size_t)(r_[0])*Tv + (kt+1)*64 + c_[0]]);
      vn1 = *reinterpret_cast<const int4*>(&Vtp[(size_t)(r_[1])*Tv + (kt+1)*64 + c_[1]]);
    }
    __syncthreads();

    // S^T: sacc[nb][reg] = S[q=q0+r16][key = kt*64 + nb*16 + g*4 + reg]
    f32x4 sacc[4];
    #pragma unroll
    for(int nb=0;nb<4;nb++){
      sacc[nb] = (f32x4){0.f,0.f,0.f,0.f};
      #pragma unroll
      for(int kb=0;kb<2;kb++){
        bf16x8 bk = *reinterpret_cast<const bf16x8*>(&Ks[nb*16+r16][kb*32+g*8]);
        sacc[nb] = __builtin_amdgcn_mfma_f32_16x16x32_bf16(bk, aq[kb], sacc[nb],0,0,0);
      }
    }

    const float SC = 0.18033688f;   // (1/8) * log2(e)  -> exp2 domain
    bool diag = (kt == qt);
    float pv[4][4];
    float mx = -1e30f;
    #pragma unroll
    for(int nb=0;nb<4;nb++)
      #pragma unroll
      for(int reg=0;reg<4;reg++){
        float s = sacc[nb][reg] * SC;
        if(diag){
          int keyin = nb*16 + g*4 + reg;
          if(keyin > wid*16 + r16) s = -1e30f;
        }
        pv[nb][reg] = s;
        mx = fmaxf(mx, s);
      }
    mx = fmaxf(mx, __shfl_xor(mx, 16, 64));
    mx = fmaxf(mx, __shfl_xor(mx, 32, 64));

    // T13 defer-max: skip rescale when growth <= 11.5 (= 8 nats)
    if(!__all(mx - m2 <= 11.5f)){
      float mn = fmaxf(m2, mx);
      float alpha = __builtin_amdgcn_exp2f(m2 - mn);
      l *= alpha;
      #pragma unroll
      for(int nb=0;nb<4;nb++)
        #pragma unroll
        for(int reg=0;reg<4;reg++) oacc[nb][reg] *= alpha;
      m2 = mn;
    }

    float rs = 0.f;
    #pragma unroll
    for(int nb=0;nb<4;nb++)
      #pragma unroll
      for(int reg=0;reg<4;reg++){
        float p = __builtin_amdgcn_exp2f(pv[nb][reg] - m2);
        pv[nb][reg] = p;
        rs += p;
      }
    rs += __shfl_xor(rs, 16, 64);
    rs += __shfl_xor(rs, 32, 64);
    l += rs;

    // P -> LDS: lane writes its 4 consecutive keys per nb as one b64
    #pragma unroll
    for(int nb=0;nb<4;nb++){
      union { uint32_t u[2]; int2 v; } w;
      w.u[0] = f2bf_fast(pv[nb][0]) | (f2bf_fast(pv[nb][1])<<16);
      w.u[1] = f2bf_fast(pv[nb][2]) | (f2bf_fast(pv[nb][3])<<16);
      *reinterpret_cast<int2*>(&Ps[wid][r16][nb*16+g*4]) = w.v;
    }

    // O^T: oacc[nb] += mfma(A=Vt rows, B=P rows)
    #pragma unroll
    for(int kb=0;kb<2;kb++){
      bf16x8 ap = *reinterpret_cast<const bf16x8*>(&Ps[wid][r16][kb*32+g*8]);
      #pragma unroll
      for(int nb=0;nb<4;nb++){
        bf16x8 bv = *reinterpret_cast<const bf16x8*>(&Vs[nb*16+r16][kb*32+g*8]);
        oacc[nb] = __builtin_amdgcn_mfma_f32_16x16x32_bf16(bv, ap, oacc[nb],0,0,0);
      }
    }
    __syncthreads();
    if(kt+1 < nkt){ kc0=kn0; kc1=kn1; vc0=vn0; vc1=vn1; }
  }

  int b = bh >> 4, h = bh & 15;
  float rinv = 1.0f / l;
  size_t row = (size_t)b*Tv + q0 + r16;
  #pragma unroll
  for(int nb=0;nb<4;nb++){
    ushort4 o;
    o.x = f2bf(oacc[nb][0]*rinv);
    o.y = f2bf(oacc[nb][1]*rinv);
    o.z = f2bf(oacc[nb][2]*rinv);
    o.w = f2bf(oacc[nb][3]*rinv);
    *reinterpret_cast<ushort4*>(&O[row*N_EMBD + h*HEADv + nb*16 + g*4]) = o;
  }
}

extern "C" void kernel_launch(void* const* d_in, const int* in_sizes, int n_in,
                              void* d_out, int out_size, void* d_ws, size_t ws_size,
                              hipStream_t stream){
  const float* x      = (const float*)d_in[0];
  const float* w_attn = (const float*)d_in[1];
  const float* b_attn = (const float*)d_in[2];
  const float* w_proj = (const float*)d_in[3];
  const float* b_proj = (const float*)d_in[4];
  char* ws = (char*)d_ws;
  unsigned short* xb  = (unsigned short*)ws;                        // 8 MB (reused as Vt after QKV GEMM)
  unsigned short* qkv = (unsigned short*)(ws + 8ll*1024*1024);      // 24 MB
  unsigned short* ob  = (unsigned short*)(ws + 32ll*1024*1024);     // 8 MB
  unsigned short* wat = (unsigned short*)(ws + 40ll*1024*1024);     // 6 MB
  unsigned short* wpt = (unsigned short*)(ws + 46ll*1024*1024);     // 2 MB
  unsigned short* vt  = xb;                                         // alias: xb dead after QKV GEMM

  k_cvt_bf16<<<2048,256,0,stream>>>(x, xb, (long)BT*N_EMBD);
  k_transpose_bf16<<<dim3(C3/64, N_EMBD/64),256,0,stream>>>(w_attn, wat, N_EMBD, C3);
  k_transpose_bf16<<<dim3(N_EMBD/64, N_EMBD/64),256,0,stream>>>(w_proj, wpt, N_EMBD, N_EMBD);
  k_gemm<0><<<dim3(C3/128, BT/128),256,0,stream>>>(xb, wat, b_attn, (void*)qkv, BT, C3, N_EMBD);
  k_transpose_v<<<dim3(Bv*N_HEADv*(Tv/64)),256,0,stream>>>(qkv + 2ll*BT*N_EMBD, vt);
  k_attn<<<dim3(Bv*N_HEADv*(Tv/64)),256,0,stream>>>(qkv, vt, ob);
  k_gemm<1><<<dim3(N_EMBD/128, BT/128),256,0,stream>>>(ob, wpt, b_proj, d_out, BT, N_EMBD, N_EMBD);
}

// Round 4
// 153.468 us; speedup vs baseline: 1.7889x; 1.1119x over previous
//
#include <hip/hip_runtime.h>
#include <stdint.h>

#define N_EMBD 1024
#define N_HEADv 16
#define HEADv 64
#define Bv 2
#define Tv 2048
#define BT (Bv*Tv)      // 4096
#define C3 (3*N_EMBD)   // 3072

typedef __attribute__((ext_vector_type(8))) short bf16x8;
typedef __attribute__((ext_vector_type(4))) float f32x4;

typedef __attribute__((address_space(3))) uint32_t lds_u32;
typedef const __attribute__((address_space(1))) uint32_t glb_u32;

__device__ __forceinline__ void gload_lds16(const void* g, void* l){
  __builtin_amdgcn_global_load_lds((glb_u32*)g, (lds_u32*)l, 16, 0, 0);
}

__device__ __forceinline__ unsigned short f2bf(float f){
  union { float f; uint32_t u; } v; v.f = f;
  uint32_t u = v.u;
  uint32_t r = u + 0x7FFFu + ((u>>16)&1u);
  return (unsigned short)(r>>16);
}
// fast round (no RNE tie-break): used for P (feeds bf16 MFMA anyway)
__device__ __forceinline__ uint32_t f2bf_fast(float f){
  union { float f; uint32_t u; } v; v.f = f;
  return (v.u + 0x8000u) >> 16;
}

// ---------------- fp32 -> bf16 elementwise ----------------
__global__ void k_cvt_bf16(const float* __restrict__ in, unsigned short* __restrict__ out, long n){
  long i = ((long)blockIdx.x*blockDim.x + threadIdx.x)*8;
  if(i >= n) return;
  float4 a = *reinterpret_cast<const float4*>(in+i);
  float4 b = *reinterpret_cast<const float4*>(in+i+4);
  union { int4 v; unsigned short s[8]; } o;
  o.s[0]=f2bf(a.x); o.s[1]=f2bf(a.y); o.s[2]=f2bf(a.z); o.s[3]=f2bf(a.w);
  o.s[4]=f2bf(b.x); o.s[5]=f2bf(b.y); o.s[6]=f2bf(b.z); o.s[7]=f2bf(b.w);
  *reinterpret_cast<int4*>(out+i) = o.v;
}

// ---------------- fp32 [K][N] -> bf16 [N][K] transpose ----------------
__global__ void k_transpose_bf16(const float* __restrict__ in, unsigned short* __restrict__ out, int K, int N){
  __shared__ float tile[64][65];
  int n0 = blockIdx.x*64, k0 = blockIdx.y*64;
  int t = threadIdx.x;
  #pragma unroll
  for(int p=0;p<4;p++){
    int row = (t>>4) + p*16;
    int col4 = (t&15)*4;
    float4 v = *reinterpret_cast<const float4*>(&in[(size_t)(k0+row)*N + n0 + col4]);
    tile[row][col4+0]=v.x; tile[row][col4+1]=v.y; tile[row][col4+2]=v.z; tile[row][col4+3]=v.w;
  }
  __syncthreads();
  #pragma unroll
  for(int p=0;p<4;p++){
    int nrow = (t>>4) + p*16;
    int kc = (t&15)*4;
    ushort4 o;
    o.x = f2bf(tile[kc+0][nrow]);
    o.y = f2bf(tile[kc+1][nrow]);
    o.z = f2bf(tile[kc+2][nrow]);
    o.w = f2bf(tile[kc+3][nrow]);
    *reinterpret_cast<ushort4*>(&out[(size_t)(n0+nrow)*K + k0 + kc]) = o;
  }
}

// ---------------- bf16 [b,h,t,d] -> bf16 [b,h,d,t] (V transpose) ----------------
__global__ __launch_bounds__(256) void k_transpose_v(const unsigned short* __restrict__ in,
                                                     unsigned short* __restrict__ out){
  __shared__ unsigned short tile[64][68];
  int bh = blockIdx.x >> 5;
  int t0 = (blockIdx.x & 31) * 64;
  const unsigned short* src = in  + (size_t)bh*Tv*HEADv;
  unsigned short*       dst = out + (size_t)bh*HEADv*Tv;
  int t = threadIdx.x;
  #pragma unroll
  for(int it=0; it<2; ++it){
    int chunk = t + it*256;        // 0..511
    int r = chunk>>3, c8 = (chunk&7)*8;     // r = token row, c8 = d col
    *reinterpret_cast<int4*>(&tile[r][c8]) =
      *reinterpret_cast<const int4*>(&src[(size_t)(t0+r)*HEADv + c8]);
  }
  __syncthreads();
  #pragma unroll
  for(int it=0; it<2; ++it){
    int chunk = t + it*256;
    int r = chunk>>3, c8 = (chunk&7)*8;     // r = d row, c8 = token col
    union { int4 v; unsigned short s[8]; } o;
    #pragma unroll
    for(int j=0;j<8;j++) o.s[j] = tile[c8+j][r];
    *reinterpret_cast<int4*>(&dst[(size_t)r*Tv + t0 + c8]) = o.v;
  }
}

// ---------------- bf16 MFMA GEMM: C = A[M][K] @ Bt[N][K]^T + bias ----------------
// global_load_lds width-16 staging, linear LDS tiles (m97 structure).
// MODE 0: scatter to QKV [3][B][H][T][D] bf16 (hoisted addressing).
// MODE 1: fp32 out [M][N], swapped-operand D^T epilogue -> float4 stores.
template<int MODE>
__global__ __launch_bounds__(256) void k_gemm(
    const unsigned short* __restrict__ A,
    const unsigned short* __restrict__ Bt,
    const float* __restrict__ bias,
    void* __restrict__ Cout,
    int M, int N, int K)
{
  const int BK=32;
  __shared__ unsigned short As[128*BK];   // linear [row][32], 64B rows (no pad: gload_lds)
  __shared__ unsigned short Bs[128*BK];
  int m0 = blockIdx.y*128, n0 = blockIdx.x*128;
  int t = threadIdx.x, lane = t&63, wid = t>>6;
  int wm = (wid>>1)*64, wn = (wid&1)*64;
  int g = lane>>4, r16 = lane&15;
  int rl = lane>>2, cl = (lane&3)*8;      // staging: lane -> (row, col8)
  f32x4 acc[4][4] = {};

  for(int k0=0;k0<K;k0+=BK){
    __syncthreads();
    #pragma unroll
    for(int i=0;i<2;i++){
      int rbase = wid*16 + i*64;
      gload_lds16(&A [(size_t)(m0+rbase+rl)*K + k0 + cl], &As[rbase*BK]);
      gload_lds16(&Bt[(size_t)(n0+rbase+rl)*K + k0 + cl], &Bs[rbase*BK]);
    }
    __syncthreads();
    bf16x8 af[4], bfr[4];
    #pragma unroll
    for(int mi=0;mi<4;mi++) af[mi]  = *reinterpret_cast<const bf16x8*>(&As[(wm+mi*16+r16)*BK + g*8]);
    #pragma unroll
    for(int ni=0;ni<4;ni++) bfr[ni] = *reinterpret_cast<const bf16x8*>(&Bs[(wn+ni*16+r16)*BK + g*8]);
    #pragma unroll
    for(int mi=0;mi<4;mi++)
      #pragma unroll
      for(int ni=0;ni<4;ni++){
        if(MODE==0)
          acc[mi][ni] = __builtin_amdgcn_mfma_f32_16x16x32_bf16(af[mi], bfr[ni], acc[mi][ni], 0,0,0);
        else  // swapped: lane holds m=r16, n=g*4+reg -> contiguous-n stores
          acc[mi][ni] = __builtin_amdgcn_mfma_f32_16x16x32_bf16(bfr[ni], af[mi], acc[mi][ni], 0,0,0);
      }
  }

  if(MODE==0){
    // wave-constant: which,h ; block-constant: b
    int which = (n0+wn)>>10;
    int h = ((n0+wn)&1023)>>6;
    int bb = m0>>11;
    int tt0 = (m0&2047) + wm;
    unsigned short* dst = (unsigned short*)Cout + (size_t)which*BT*N_EMBD
                        + (((size_t)bb*N_HEADv + h)*Tv + tt0)*HEADv;
    #pragma unroll
    for(int ni=0;ni<4;ni++){
      float bv = bias[n0+wn+ni*16+r16];
      int d = ni*16 + r16;
      #pragma unroll
      for(int mi=0;mi<4;mi++){
        #pragma unroll
        for(int reg=0;reg<4;reg++){
          int tt = mi*16 + g*4 + reg;
          dst[(size_t)tt*HEADv + d] = f2bf(acc[mi][ni][reg] + bv);
        }
      }
    }
  } else {
    float* out = (float*)Cout;
    #pragma unroll
    for(int mi=0;mi<4;mi++){
      int m = m0+wm+mi*16+r16;
      #pragma unroll
      for(int ni=0;ni<4;ni++){
        int n = n0+wn+ni*16+g*4;
        float4 b4 = *reinterpret_cast<const float4*>(&bias[n]);
        float4 o4;
        o4.x = acc[mi][ni][0] + b4.x;
        o4.y = acc[mi][ni][1] + b4.y;
        o4.z = acc[mi][ni][2] + b4.z;
        o4.w = acc[mi][ni][3] + b4.w;
        *reinterpret_cast<float4*>(&out[(size_t)m*N + n]) = o4;
      }
    }
  }
}

// ---------------- flash attention (causal), swapped-operand form ----------------
// Q,K bf16 [B,H,T,D] (inside QKV); Vt bf16 [B,H,D,T]; O bf16 [B*T][C]
// Double-buffered K/V LDS, XOR-swizzled 128B rows, ONE barrier per iter.
__global__ __launch_bounds__(256) void k_attn(
    const unsigned short* __restrict__ QKV,
    const unsigned short* __restrict__ VT,
    unsigned short* __restrict__ O)
{
  __shared__ unsigned short Ks[2][64][64];   // Ks[buf][key][d]   (swizzled cols)
  __shared__ unsigned short Vs[2][64][64];   // Vs[buf][d][key]
  __shared__ unsigned short Ps[4][16][64];   // Ps[wave][q][key]
  int blk = blockIdx.x;
  int qt = 31 - (blk & 31);     // longest blocks first
  int bh = blk >> 5;            // b*H + h
  int t = threadIdx.x, lane=t&63, wid=t>>6;
  int g = lane>>4, r16 = lane&15;
  const size_t headoff = (size_t)bh*Tv*HEADv;
  const unsigned short* Qp  = QKV + headoff;
  const unsigned short* Kp  = QKV + (size_t)BT*N_EMBD + headoff;
  const unsigned short* Vtp = VT + (size_t)bh*HEADv*Tv;
  int q0 = qt*64 + wid*16;

  bf16x8 aq[2];   // B-operand: col = q = r16
  #pragma unroll
  for(int kb=0;kb<2;kb++)
    aq[kb] = *reinterpret_cast<const bf16x8*>(&Qp[(size_t)(q0+r16)*HEADv + kb*32 + g*8]);

  f32x4 oacc[4] = {};          // oacc[nb][reg] = O[q=q0+r16][d=nb*16+g*4+reg]
  float m2 = -1e30f, l = 0.f;  // per-lane scalar stats (log2 domain)

  const int nkt = qt+1;
  // staging: thread covers chunks t (rows 0..31) and t+256 (rows 32..63)
  int r0 = t>>3, c0 = (t&7)*8;
  int r1 = r0 + 32;
  int sw0 = c0 ^ ((r0&7)<<3);
  int sw1 = c0 ^ ((r1&7)<<3);
  int rsw = (r16&7)<<3;          // read-side swizzle (row = *+r16)

  // prologue: tile 0 -> regs -> buf0 ; issue tile 1 loads
  int4 kc0, kc1, vc0, vc1;
  kc0 = *reinterpret_cast<const int4*>(&Kp [(size_t)r0*HEADv + c0]);
  kc1 = *reinterpret_cast<const int4*>(&Kp [(size_t)r1*HEADv + c0]);
  vc0 = *reinterpret_cast<const int4*>(&Vtp[(size_t)r0*Tv + c0]);
  vc1 = *reinterpret_cast<const int4*>(&Vtp[(size_t)r1*Tv + c0]);
  *reinterpret_cast<int4*>(&Ks[0][r0][sw0]) = kc0;
  *reinterpret_cast<int4*>(&Ks[0][r1][sw1]) = kc1;
  *reinterpret_cast<int4*>(&Vs[0][r0][sw0]) = vc0;
  *reinterpret_cast<int4*>(&Vs[0][r1][sw1]) = vc1;
  if(nkt > 1){
    kc0 = *reinterpret_cast<const int4*>(&Kp [(size_t)(64+r0)*HEADv + c0]);
    kc1 = *reinterpret_cast<const int4*>(&Kp [(size_t)(64+r1)*HEADv + c0]);
    vc0 = *reinterpret_cast<const int4*>(&Vtp[(size_t)r0*Tv + 64 + c0]);
    vc1 = *reinterpret_cast<const int4*>(&Vtp[(size_t)r1*Tv + 64 + c0]);
  }
  __syncthreads();

  for(int kt=0; kt<nkt; ++kt){
    int cur = kt & 1;
    if(kt+1 < nkt){
      // write next tile to the other buffer (its readers passed last barrier)
      *reinterpret_cast<int4*>(&Ks[cur^1][r0][sw0]) = kc0;
      *reinterpret_cast<int4*>(&Ks[cur^1][r1][sw1]) = kc1;
      *reinterpret_cast<int4*>(&Vs[cur^1][r0][sw0]) = vc0;
      *reinterpret_cast<int4*>(&Vs[cur^1][r1][sw1]) = vc1;
      if(kt+2 < nkt){
        kc0 = *reinterpret_cast<const int4*>(&Kp [(size_t)((kt+2)*64+r0)*HEADv + c0]);
        kc1 = *reinterpret_cast<const int4*>(&Kp [(size_t)((kt+2)*64+r1)*HEADv + c0]);
        vc0 = *reinterpret_cast<const int4*>(&Vtp[(size_t)r0*Tv + (kt+2)*64 + c0]);
        vc1 = *reinterpret_cast<const int4*>(&Vtp[(size_t)r1*Tv + (kt+2)*64 + c0]);
      }
    }

    // S^T: sacc[nb][reg] = S[q=q0+r16][key = kt*64 + nb*16 + g*4 + reg]
    f32x4 sacc[4];
    __builtin_amdgcn_s_setprio(1);
    #pragma unroll
    for(int nb=0;nb<4;nb++){
      sacc[nb] = (f32x4){0.f,0.f,0.f,0.f};
      #pragma unroll
      for(int kb=0;kb<2;kb++){
        bf16x8 bk = *reinterpret_cast<const bf16x8*>(&Ks[cur][nb*16+r16][(kb*32+g*8) ^ rsw]);
        sacc[nb] = __builtin_amdgcn_mfma_f32_16x16x32_bf16(bk, aq[kb], sacc[nb],0,0,0);
      }
    }
    __builtin_amdgcn_s_setprio(0);

    const float SC = 0.18033688f;   // (1/8) * log2(e)  -> exp2 domain
    bool diag = (kt == qt);
    float pv[4][4];
    float mx = -1e30f;
    #pragma unroll
    for(int nb=0;nb<4;nb++)
      #pragma unroll
      for(int reg=0;reg<4;reg++){
        float s = sacc[nb][reg] * SC;
        if(diag){
          int keyin = nb*16 + g*4 + reg;
          if(keyin > wid*16 + r16) s = -1e30f;
        }
        pv[nb][reg] = s;
        mx = fmaxf(mx, s);
      }
    mx = fmaxf(mx, __shfl_xor(mx, 16, 64));
    mx = fmaxf(mx, __shfl_xor(mx, 32, 64));

    // T13 defer-max: skip rescale when growth <= 11.5 (= 8 nats)
    if(!__all(mx - m2 <= 11.5f)){
      float mn = fmaxf(m2, mx);
      float alpha = __builtin_amdgcn_exp2f(m2 - mn);
      l *= alpha;
      #pragma unroll
      for(int nb=0;nb<4;nb++)
        #pragma unroll
        for(int reg=0;reg<4;reg++) oacc[nb][reg] *= alpha;
      m2 = mn;
    }

    float rs = 0.f;
    #pragma unroll
    for(int nb=0;nb<4;nb++)
      #pragma unroll
      for(int reg=0;reg<4;reg++){
        float p = __builtin_amdgcn_exp2f(pv[nb][reg] - m2);
        pv[nb][reg] = p;
        rs += p;
      }
    rs += __shfl_xor(rs, 16, 64);
    rs += __shfl_xor(rs, 32, 64);
    l += rs;

    // P -> LDS (wave-private, swizzled): lane writes 4 keys per nb as one b64
    #pragma unroll
    for(int nb=0;nb<4;nb++){
      union { uint32_t u[2]; int2 v; } w;
      w.u[0] = f2bf_fast(pv[nb][0]) | (f2bf_fast(pv[nb][1])<<16);
      w.u[1] = f2bf_fast(pv[nb][2]) | (f2bf_fast(pv[nb][3])<<16);
      *reinterpret_cast<int2*>(&Ps[wid][r16][(nb*16+g*4) ^ rsw]) = w.v;
    }

    // O^T: oacc[nb] += mfma(A=Vt rows, B=P rows)
    __builtin_amdgcn_s_setprio(1);
    #pragma unroll
    for(int kb=0;kb<2;kb++){
      bf16x8 ap = *reinterpret_cast<const bf16x8*>(&Ps[wid][r16][(kb*32+g*8) ^ rsw]);
      #pragma unroll
      for(int nb=0;nb<4;nb++){
        bf16x8 bv = *reinterpret_cast<const bf16x8*>(&Vs[cur][nb*16+r16][(kb*32+g*8) ^ rsw]);
        oacc[nb] = __builtin_amdgcn_mfma_f32_16x16x32_bf16(bv, ap, oacc[nb],0,0,0);
      }
    }
    __builtin_amdgcn_s_setprio(0);
    __syncthreads();
  }

  int b = bh >> 4, h = bh & 15;
  float rinv = 1.0f / l;
  size_t row = (size_t)b*Tv + q0 + r16;
  #pragma unroll
  for(int nb=0;nb<4;nb++){
    ushort4 o;
    o.x = f2bf(oacc[nb][0]*rinv);
    o.y = f2bf(oacc[nb][1]*rinv);
    o.z = f2bf(oacc[nb][2]*rinv);
    o.w = f2bf(oacc[nb][3]*rinv);
    *reinterpret_cast<ushort4*>(&O[row*N_EMBD + h*HEADv + nb*16 + g*4]) = o;
  }
}

extern "C" void kernel_launch(void* const* d_in, const int* in_sizes, int n_in,
                              void* d_out, int out_size, void* d_ws, size_t ws_size,
                              hipStream_t stream){
  const float* x      = (const float*)d_in[0];
  const float* w_attn = (const float*)d_in[1];
  const float* b_attn = (const float*)d_in[2];
  const float* w_proj = (const float*)d_in[3];
  const float* b_proj = (const float*)d_in[4];
  char* ws = (char*)d_ws;
  unsigned short* xb  = (unsigned short*)ws;                        // 8 MB (reused as Vt after QKV GEMM)
  unsigned short* qkv = (unsigned short*)(ws + 8ll*1024*1024);      // 24 MB
  unsigned short* ob  = (unsigned short*)(ws + 32ll*1024*1024);     // 8 MB
  unsigned short* wat = (unsigned short*)(ws + 40ll*1024*1024);     // 6 MB
  unsigned short* wpt = (unsigned short*)(ws + 46ll*1024*1024);     // 2 MB
  unsigned short* vt  = xb;                                         // alias: xb dead after QKV GEMM

  k_cvt_bf16<<<2048,256,0,stream>>>(x, xb, (long)BT*N_EMBD);
  k_transpose_bf16<<<dim3(C3/64, N_EMBD/64),256,0,stream>>>(w_attn, wat, N_EMBD, C3);
  k_transpose_bf16<<<dim3(N_EMBD/64, N_EMBD/64),256,0,stream>>>(w_proj, wpt, N_EMBD, N_EMBD);
  k_gemm<0><<<dim3(C3/128, BT/128),256,0,stream>>>(xb, wat, b_attn, (void*)qkv, BT, C3, N_EMBD);
  k_transpose_v<<<dim3(Bv*N_HEADv*(Tv/64)),256,0,stream>>>(qkv + 2ll*BT*N_EMBD, vt);
  k_attn<<<dim3(Bv*N_HEADv*(Tv/64)),256,0,stream>>>(qkv, vt, ob);
  k_gemm<1><<<dim3(N_EMBD/128, BT/128),256,0,stream>>>(ob, wpt, b_proj, d_out, BT, N_EMBD, N_EMBD);
}